// Round 1
// baseline (86.203 us; speedup 1.0000x reference)
//
#include <hip/hip_runtime.h>
#include <math.h>

#define BB 4
#define NN 5
#define CC_DIM 64
#define HH 100
#define WW 252
#define HW (HH * WW)
#define CPT 8              // channels per thread
#define NCHUNK (CC_DIM / CPT)  // 8 chunks

__global__ __launch_bounds__(256) void where2comm_fuse_kernel(
    const float* __restrict__ x,    // (B*N, C, H, W)
    const float* __restrict__ ptm,  // (B, N, N, 2, 3)
    float* __restrict__ out)        // (B, C, H, W) + 1 scalar
{
    const int idx = blockIdx.x * blockDim.x + threadIdx.x;
    const int total = BB * NCHUNK * HH * WW;   // 806400
    if (idx >= total) {
        return;
    }

    // decompose: w fastest (coalescing), then h, then channel-chunk, then b
    int w = idx % WW;
    int t = idx / WW;
    int h = t % HH;
    t /= HH;
    int cc = t % NCHUNK;
    int b = t / NCHUNK;

    // normalized grid coords (match reference formulas exactly)
    float gx = (2.0f * (float)w + 1.0f) / (float)WW - 1.0f;
    float gy = (2.0f * (float)h + 1.0f) / (float)HH - 1.0f;

    float acc[CPT];
#pragma unroll
    for (int c = 0; c < CPT; ++c) acc[c] = -INFINITY;

    // theta = ptm[b, 0, n, :, :]
    const float* th_b = ptm + (size_t)b * (NN * NN * 6);

    for (int n = 0; n < NN; ++n) {
        const float t00 = th_b[n * 6 + 0];
        const float t01 = th_b[n * 6 + 1];
        const float t02 = th_b[n * 6 + 2];
        const float t10 = th_b[n * 6 + 3];
        const float t11 = th_b[n * 6 + 4];
        const float t12 = th_b[n * 6 + 5];

        const float cx = t00 * gx + t01 * gy + t02;
        const float cy = t10 * gx + t11 * gy + t12;

        const float ix = ((cx + 1.0f) * (float)WW - 1.0f) * 0.5f;
        const float iy = ((cy + 1.0f) * (float)HH - 1.0f) * 0.5f;

        const float x0f = floorf(ix);
        const float y0f = floorf(iy);
        const float x1f = x0f + 1.0f;
        const float y1f = y0f + 1.0f;

        const float wx1 = ix - x0f;
        const float wx0 = 1.0f - wx1;
        const float wy1 = iy - y0f;
        const float wy0 = 1.0f - wy1;

        // validity per corner (zero-padding semantics)
        const float mx0 = (x0f >= 0.0f && x0f <= (float)(WW - 1)) ? 1.0f : 0.0f;
        const float mx1 = (x1f >= 0.0f && x1f <= (float)(WW - 1)) ? 1.0f : 0.0f;
        const float my0 = (y0f >= 0.0f && y0f <= (float)(HH - 1)) ? 1.0f : 0.0f;
        const float my1 = (y1f >= 0.0f && y1f <= (float)(HH - 1)) ? 1.0f : 0.0f;

        // clamp-then-cast (matches jnp.clip(...).astype(int32))
        const int xi0 = (int)fminf(fmaxf(x0f, 0.0f), (float)(WW - 1));
        const int xi1 = (int)fminf(fmaxf(x1f, 0.0f), (float)(WW - 1));
        const int yi0 = (int)fminf(fmaxf(y0f, 0.0f), (float)(HH - 1));
        const int yi1 = (int)fminf(fmaxf(y1f, 0.0f), (float)(HH - 1));

        // effective corner weights (weight * validity)
        const float e00 = wx0 * wy0 * mx0 * my0;
        const float e10 = wx1 * wy0 * mx1 * my0;
        const float e01 = wx0 * wy1 * mx0 * my1;
        const float e11 = wx1 * wy1 * mx1 * my1;

        const int o00 = yi0 * WW + xi0;
        const int o10 = yi0 * WW + xi1;
        const int o01 = yi1 * WW + xi0;
        const int o11 = yi1 * WW + xi1;

        const float* p = x + ((size_t)(b * NN + n) * CC_DIM + cc * CPT) * HW;

#pragma unroll
        for (int c = 0; c < CPT; ++c) {
            const float* pc = p + (size_t)c * HW;
            float v = pc[o00] * e00;
            v = fmaf(pc[o10], e10, v);
            v = fmaf(pc[o01], e01, v);
            v = fmaf(pc[o11], e11, v);
            acc[c] = fmaxf(acc[c], v);
        }
    }

    // write outputs: out[b, cc*CPT + c, h, w]
#pragma unroll
    for (int c = 0; c < CPT; ++c) {
        out[(((size_t)b * CC_DIM + cc * CPT + c) * HH + h) * WW + w] = acc[c];
    }

    if (idx == 0) {
        out[(size_t)BB * CC_DIM * HW] = 0.0f;  // communication_rates
    }
}

extern "C" void kernel_launch(void* const* d_in, const int* in_sizes, int n_in,
                              void* d_out, int out_size, void* d_ws, size_t ws_size,
                              hipStream_t stream) {
    const float* x = (const float*)d_in[0];
    const float* ptm = (const float*)d_in[3];
    float* out = (float*)d_out;

    const int total = BB * NCHUNK * HH * WW;  // 806400
    const int block = 256;
    const int grid = (total + block - 1) / block;  // 3150
    where2comm_fuse_kernel<<<grid, block, 0, stream>>>(x, ptm, out);
}

// Round 2
// 58.025 us; speedup vs baseline: 1.4856x; 1.4856x over previous
//
#include <hip/hip_runtime.h>
#include <math.h>

#define BB 4
#define NN 5
#define CC_DIM 64
#define HH 100
#define WW 252
#define HW (HH * WW)
#define CPT 8              // channels per thread
#define NCHUNK (CC_DIM / CPT)  // 8 chunks

__global__ __launch_bounds__(256) void where2comm_fuse_kernel(
    const float* __restrict__ x,    // (B*N, C, H, W)
    const float* __restrict__ ptm,  // (B, N, N, 2, 3)
    float* __restrict__ out)        // (B, C, H, W) + 1 scalar
{
    const int idx = blockIdx.x * blockDim.x + threadIdx.x;
    const int total = BB * NCHUNK * HH * WW;   // 806400
    if (idx >= total) {
        return;
    }

    // decompose: w fastest (coalescing), then h, then channel-chunk, then b
    int w = idx % WW;
    int t = idx / WW;
    int h = t % HH;
    t /= HH;
    int cc = t % NCHUNK;
    int b = t / NCHUNK;

    // normalized grid coords (match reference formulas exactly)
    const float gx = (2.0f * (float)w + 1.0f) / (float)WW - 1.0f;
    const float gy = (2.0f * (float)h + 1.0f) / (float)HH - 1.0f;

    float acc[CPT];
#pragma unroll
    for (int c = 0; c < CPT; ++c) acc[c] = -INFINITY;

    // theta = ptm[b, 0, n, :, :]
    const float* th_b = ptm + (size_t)b * (NN * NN * 6);

#pragma unroll
    for (int n = 0; n < NN; ++n) {
        const float t00 = th_b[n * 6 + 0];
        const float t01 = th_b[n * 6 + 1];
        const float t02 = th_b[n * 6 + 2];
        const float t10 = th_b[n * 6 + 3];
        const float t11 = th_b[n * 6 + 4];
        const float t12 = th_b[n * 6 + 5];

        const float cx = t00 * gx + t01 * gy + t02;
        const float cy = t10 * gx + t11 * gy + t12;

        const float ix = ((cx + 1.0f) * (float)WW - 1.0f) * 0.5f;
        const float iy = ((cy + 1.0f) * (float)HH - 1.0f) * 0.5f;

        const float x0f = floorf(ix);
        const float y0f = floorf(iy);
        const float x1f = x0f + 1.0f;
        const float y1f = y0f + 1.0f;

        const float wx1 = ix - x0f;
        const float wx0 = 1.0f - wx1;
        const float wy1 = iy - y0f;
        const float wy0 = 1.0f - wy1;

        // validity per corner (zero-padding semantics)
        const float mx0 = (x0f >= 0.0f && x0f <= (float)(WW - 1)) ? 1.0f : 0.0f;
        const float mx1 = (x1f >= 0.0f && x1f <= (float)(WW - 1)) ? 1.0f : 0.0f;
        const float my0 = (y0f >= 0.0f && y0f <= (float)(HH - 1)) ? 1.0f : 0.0f;
        const float my1 = (y1f >= 0.0f && y1f <= (float)(HH - 1)) ? 1.0f : 0.0f;

        // clamp-then-cast (matches jnp.clip(...).astype(int32))
        const int xi0 = (int)fminf(fmaxf(x0f, 0.0f), (float)(WW - 1));
        const int xi1 = (int)fminf(fmaxf(x1f, 0.0f), (float)(WW - 1));
        const int yi0 = (int)fminf(fmaxf(y0f, 0.0f), (float)(HH - 1));
        const int yi1 = (int)fminf(fmaxf(y1f, 0.0f), (float)(HH - 1));

        // effective corner weights (weight * validity)
        const float e00 = wx0 * wy0 * mx0 * my0;
        const float e10 = wx1 * wy0 * mx1 * my0;
        const float e01 = wx0 * wy1 * mx0 * my1;
        const float e11 = wx1 * wy1 * mx1 * my1;

        const int o00 = yi0 * WW + xi0;
        const int o10 = yi0 * WW + xi1;
        const int o01 = yi1 * WW + xi0;
        const int o11 = yi1 * WW + xi1;

        const float* p = x + ((size_t)(b * NN + n) * CC_DIM + cc * CPT) * HW;

        // ---- phase 1: issue ALL 32 loads for this agent (maximize MLP) ----
        float v00[CPT], v10[CPT], v01[CPT], v11[CPT];
#pragma unroll
        for (int c = 0; c < CPT; ++c) {
            const float* pc = p + (size_t)c * HW;
            v00[c] = pc[o00];
            v10[c] = pc[o10];
            v01[c] = pc[o01];
            v11[c] = pc[o11];
        }

        // ---- phase 2: consume ----
#pragma unroll
        for (int c = 0; c < CPT; ++c) {
            float v = v00[c] * e00;
            v = fmaf(v10[c], e10, v);
            v = fmaf(v01[c], e01, v);
            v = fmaf(v11[c], e11, v);
            acc[c] = fmaxf(acc[c], v);
        }
    }

    // write outputs: out[b, cc*CPT + c, h, w]
#pragma unroll
    for (int c = 0; c < CPT; ++c) {
        out[(((size_t)b * CC_DIM + cc * CPT + c) * HH + h) * WW + w] = acc[c];
    }

    if (idx == 0) {
        out[(size_t)BB * CC_DIM * HW] = 0.0f;  // communication_rates
    }
}

extern "C" void kernel_launch(void* const* d_in, const int* in_sizes, int n_in,
                              void* d_out, int out_size, void* d_ws, size_t ws_size,
                              hipStream_t stream) {
    const float* x = (const float*)d_in[0];
    const float* ptm = (const float*)d_in[3];
    float* out = (float*)d_out;

    const int total = BB * NCHUNK * HH * WW;  // 806400
    const int block = 256;
    const int grid = (total + block - 1) / block;  // 3150
    where2comm_fuse_kernel<<<grid, block, 0, stream>>>(x, ptm, out);
}